// Round 1
// baseline (1020.432 us; speedup 1.0000x reference)
//
#include <hip/hip_runtime.h>
#include <hip/hip_bf16.h>

// Shapes (fixed by the reference): B=2 T=1024 E=1024 H=8 W=31 D=63
//   NTOK = B*T = 2048, H*D = 504, 3*H*D = 1512, 4E = 4096

// ---------------- rotary: xr = [sin(x*invf) | cos(x*invf)] ----------------
__global__ __launch_bounds__(256) void rotary_kernel(
    const float* __restrict__ x, float* __restrict__ xr)
{
    int row = blockIdx.x;                       // 0..2047
    const float* xp = x + (size_t)row * 512;
    float* yp = xr + (size_t)row * 1024;
    for (int j = threadIdx.x; j < 512; j += 256) {
        // inv_freq = 10000^(-j/512) = exp2(-j * log2(10000)/512)
        float invf = exp2f(-(float)j * 0.025952563241307518f);
        float ang = xp[j] * invf;
        yp[j]       = sinf(ang);
        yp[j + 512] = cosf(ang);
    }
}

// ---------------- layernorm over 1024 cols, one block per row -------------
__global__ __launch_bounds__(256) void ln_kernel(
    const float* __restrict__ X, const float* __restrict__ w,
    const float* __restrict__ b, float* __restrict__ Y)
{
    int row = blockIdx.x;
    const float4* xp = (const float4*)(X + (size_t)row * 1024);
    float4 xv = xp[threadIdx.x];
    float s  = xv.x + xv.y + xv.z + xv.w;
    float ss = xv.x*xv.x + xv.y*xv.y + xv.z*xv.z + xv.w*xv.w;
    #pragma unroll
    for (int off = 32; off > 0; off >>= 1) {
        s  += __shfl_down(s, off);
        ss += __shfl_down(ss, off);
    }
    __shared__ float rs[4], rss[4];
    int wave = threadIdx.x >> 6, lane = threadIdx.x & 63;
    if (lane == 0) { rs[wave] = s; rss[wave] = ss; }
    __syncthreads();
    s  = rs[0] + rs[1] + rs[2] + rs[3];
    ss = rss[0] + rss[1] + rss[2] + rss[3];
    float mu  = s * (1.f / 1024.f);
    float var = ss * (1.f / 1024.f) - mu * mu;
    float rstd = rsqrtf(var + 1e-5f);
    float4 wv = ((const float4*)w)[threadIdx.x];
    float4 bv = ((const float4*)b)[threadIdx.x];
    float4 y;
    y.x = (xv.x - mu) * rstd * wv.x + bv.x;
    y.y = (xv.y - mu) * rstd * wv.y + bv.y;
    y.z = (xv.z - mu) * rstd * wv.z + bv.z;
    y.w = (xv.w - mu) * rstd * wv.w + bv.w;
    ((float4*)(Y + (size_t)row * 1024))[threadIdx.x] = y;
}

// ---------------- fp32 tiled GEMM: C = A[M,K] @ W[N,K]^T + bias ------------
// EPI: 0 = none, 1 = exact gelu, 2 = += R (residual)
__device__ __forceinline__ float gelu_exact(float v)
{
    return 0.5f * v * (1.f + erff(v * 0.70710678118654752f));
}

template<int EPI>
__global__ __launch_bounds__(256) void gemm_kernel(
    const float* __restrict__ A, const float* __restrict__ W,
    const float* __restrict__ bias, const float* R,
    float* C, int M, int N, int K)
{
    __shared__ __align__(16) float As[16][136];
    __shared__ __align__(16) float Ws[16][136];
    const int tid  = threadIdx.x;
    const int row0 = blockIdx.y * 128;
    const int col0 = blockIdx.x * 128;
    const int lr = tid >> 1;            // 0..127 : tile row for loads
    const int lk = (tid & 1) << 3;      // 0 or 8 : k offset for loads
    const int ty = tid >> 4;            // 0..15
    const int tx = tid & 15;            // 0..15
    float acc[8][8] = {};
    const int ntiles = (K + 15) >> 4;
    for (int t = 0; t < ntiles; ++t) {
        const int k0 = t << 4;
        float4 a0 = make_float4(0.f,0.f,0.f,0.f), a1 = a0, w0 = a0, w1 = a0;
        if (k0 + lk < K) {   // K is a multiple of 8 for all call sites
            const float* ap = A + (size_t)(row0 + lr) * K + k0 + lk;
            a0 = *(const float4*)ap;
            a1 = *(const float4*)(ap + 4);
        }
        if ((col0 + lr) < N && (k0 + lk) < K) {
            const float* wp = W + (size_t)(col0 + lr) * K + k0 + lk;
            w0 = *(const float4*)wp;
            w1 = *(const float4*)(wp + 4);
        }
        __syncthreads();   // protect LDS from previous iteration's readers
        As[lk+0][lr] = a0.x; As[lk+1][lr] = a0.y; As[lk+2][lr] = a0.z; As[lk+3][lr] = a0.w;
        As[lk+4][lr] = a1.x; As[lk+5][lr] = a1.y; As[lk+6][lr] = a1.z; As[lk+7][lr] = a1.w;
        Ws[lk+0][lr] = w0.x; Ws[lk+1][lr] = w0.y; Ws[lk+2][lr] = w0.z; Ws[lk+3][lr] = w0.w;
        Ws[lk+4][lr] = w1.x; Ws[lk+5][lr] = w1.y; Ws[lk+6][lr] = w1.z; Ws[lk+7][lr] = w1.w;
        __syncthreads();
        #pragma unroll
        for (int kk = 0; kk < 16; ++kk) {
            float a[8], bb[8];
            *(float4*)&a[0]  = *(const float4*)&As[kk][ty*8];
            *(float4*)&a[4]  = *(const float4*)&As[kk][ty*8+4];
            *(float4*)&bb[0] = *(const float4*)&Ws[kk][tx*8];
            *(float4*)&bb[4] = *(const float4*)&Ws[kk][tx*8+4];
            #pragma unroll
            for (int i = 0; i < 8; ++i)
                #pragma unroll
                for (int j = 0; j < 8; ++j)
                    acc[i][j] = fmaf(a[i], bb[j], acc[i][j]);
        }
    }
    #pragma unroll
    for (int i = 0; i < 8; ++i) {
        int row = row0 + ty*8 + i;       // M = 2048 -> always in range
        float* cp = C + (size_t)row * N + col0 + tx*8;
        #pragma unroll
        for (int jj = 0; jj < 8; jj += 4) {
            int col = col0 + tx*8 + jj;
            if (col < N) {               // N % 4 == 0, col % 4 == 0
                float4 bv = *(const float4*)(bias + col);
                float4 c;
                c.x = acc[i][jj+0] + bv.x;
                c.y = acc[i][jj+1] + bv.y;
                c.z = acc[i][jj+2] + bv.z;
                c.w = acc[i][jj+3] + bv.w;
                if (EPI == 1) {
                    c.x = gelu_exact(c.x); c.y = gelu_exact(c.y);
                    c.z = gelu_exact(c.z); c.w = gelu_exact(c.w);
                }
                if (EPI == 2) {
                    float4 r = *(const float4*)(R + (size_t)row * N + col0 + tx*8 + jj);
                    c.x += r.x; c.y += r.y; c.z += r.z; c.w += r.w;
                }
                *(float4*)(cp + jj) = c;
            }
        }
    }
}

// ---------------- windowed attention, one wave per (b,h,t) token ----------
// scores[d,v] = q[d]*k[v] + bias[d,v];  softmax over d (axis=-2);
// out[d] = sum_v exp(s[d,v]-m[v]) * (v[v]/Z[v])
__global__ __launch_bounds__(256) void attn_kernel(
    const float* __restrict__ qkv, const float* __restrict__ rel_pos,
    float* __restrict__ outp)
{
    __shared__ float sbias[64*65];       // bias[d][v] at d*65+v (pad -> (d+v)%32 banks)
    __shared__ float kmw[4][3][64];      // per wave: k[], m[], w[]
    for (int i = threadIdx.x; i < 63*63; i += 256) {
        int d = i / 63, v = i - d*63;
        sbias[d*65 + v] = rel_pos[((d + 32) % 63) * 63 + v];  // row perm (i-31) mod 63
    }
    __syncthreads();
    const int wave = threadIdx.x >> 6;
    const int lane = threadIdx.x & 63;
    const int tk  = blockIdx.x * 4 + wave;   // 0..16383
    const int row = tk >> 3;                 // b*T + t
    const int h   = tk & 7;
    const float* base = qkv + (size_t)row * 1512 + h * 63;
    float q_own = 0.f, k_own = 0.f, v_own = 0.f;
    if (lane < 63) {
        q_own = base[lane];
        k_own = base[504 + lane];
        v_own = base[1008 + lane];
    }
    // phase A: lane = column v. per-column max and exp-sum over d.
    float m = -1e30f;
    for (int d = 0; d < 63; ++d) {
        float qd = __shfl(q_own, d);
        float s = fmaf(qd, k_own, sbias[d*65 + lane]);
        m = fmaxf(m, s);
    }
    float Z = 0.f;
    for (int d = 0; d < 63; ++d) {
        float qd = __shfl(q_own, d);
        float s = fmaf(qd, k_own, sbias[d*65 + lane]);
        Z += __expf(s - m);
    }
    kmw[wave][0][lane] = k_own;
    kmw[wave][1][lane] = m;
    kmw[wave][2][lane] = v_own / Z;
    // same-wave LDS write->read: program order, no barrier needed
    // phase B: lane = row d. out[d] = sum_v exp(q_d*k_v + bias[d,v] - m[v]) * w[v]
    float acc = 0.f;
    for (int v = 0; v < 63; ++v) {
        float s = fmaf(q_own, kmw[wave][0][v], sbias[lane*65 + v]) - kmw[wave][1][v];
        acc += __expf(s) * kmw[wave][2][v];
    }
    if (lane < 63)
        outp[(size_t)row * 504 + h*63 + lane] = acc;
}

extern "C" void kernel_launch(void* const* d_in, const int* in_sizes, int n_in,
                              void* d_out, int out_size, void* d_ws, size_t ws_size,
                              hipStream_t stream)
{
    const float* x       = (const float*)d_in[0];
    const float* ln1_w   = (const float*)d_in[1];
    const float* ln1_b   = (const float*)d_in[2];
    const float* qkv_w   = (const float*)d_in[3];
    const float* qkv_b   = (const float*)d_in[4];
    const float* rel_pos = (const float*)d_in[5];
    const float* proj_w  = (const float*)d_in[6];
    const float* proj_b  = (const float*)d_in[7];
    const float* ln2_w   = (const float*)d_in[8];
    const float* ln2_b   = (const float*)d_in[9];
    const float* fc_w    = (const float*)d_in[10];
    const float* fc_b    = (const float*)d_in[11];
    const float* cproj_w = (const float*)d_in[12];
    const float* cproj_b = (const float*)d_in[13];
    float* out = (float*)d_out;

    // workspace layout (floats); fc_act aliases qkv (qkv dead after attn)
    float* ws     = (float*)d_ws;
    float* xr     = ws;                         // 2048*1024
    float* hbuf   = xr + 2048*1024;             // 2048*1024 (h, then h2)
    float* qkv    = hbuf + 2048*1024;           // 2048*1512
    float* fc_act = qkv;                        // 2048*4096 (reuse, after attn)
    float* attn_o = fc_act + 2048*4096;         // 2048*504
    // total: (2+2+8)*2048*1024*? -> 13,615,104 floats = 54.5 MB

    rotary_kernel<<<2048, 256, 0, stream>>>(x, xr);
    ln_kernel<<<2048, 256, 0, stream>>>(xr, ln1_w, ln1_b, hbuf);
    gemm_kernel<0><<<dim3(12,16), 256, 0, stream>>>(hbuf, qkv_w, qkv_b, nullptr, qkv,
                                                    2048, 1512, 1024);
    attn_kernel<<<4096, 256, 0, stream>>>(qkv, rel_pos, attn_o);
    gemm_kernel<2><<<dim3(8,16), 256, 0, stream>>>(attn_o, proj_w, proj_b, xr, out,
                                                   2048, 1024, 504);
    ln_kernel<<<2048, 256, 0, stream>>>(out, ln2_w, ln2_b, hbuf);
    gemm_kernel<1><<<dim3(32,16), 256, 0, stream>>>(hbuf, fc_w, fc_b, nullptr, fc_act,
                                                    2048, 4096, 1024);
    gemm_kernel<2><<<dim3(8,16), 256, 0, stream>>>(fc_act, cproj_w, cproj_b, out, out,
                                                   2048, 1024, 4096);
}

// Round 2
// 254.555 us; speedup vs baseline: 4.0087x; 4.0087x over previous
//
#include <hip/hip_runtime.h>
#include <hip/hip_bf16.h>

// Shapes (fixed): B=2 T=1024 E=1024 H=8 W=31 D=63
// NTOK=2048, H*D=504 (pad 512), 3*H*D=1512 (pad 1536), 4E=4096

typedef __bf16 bf16;
typedef bf16 bf16x8 __attribute__((ext_vector_type(8)));
typedef bf16 bf16x4 __attribute__((ext_vector_type(4)));
typedef float f32x4 __attribute__((ext_vector_type(4)));

// ---------------- rotary: xr = [sin(x*invf) | cos(x*invf)] (fp32 out) ------
__global__ __launch_bounds__(256) void rotary_kernel(
    const float* __restrict__ x, float* __restrict__ xr)
{
    int row = blockIdx.x;
    const float* xp = x + (size_t)row * 512;
    float* yp = xr + (size_t)row * 1024;
    for (int j = threadIdx.x; j < 512; j += 256) {
        float invf = exp2f(-(float)j * 0.025952563241307518f); // 10000^(-j/512)
        float ang = xp[j] * invf;
        yp[j]       = sinf(ang);
        yp[j + 512] = cosf(ang);
    }
}

// ---------------- layernorm (fp32 in, bf16 out), one block per row --------
__global__ __launch_bounds__(256) void ln_bf16_kernel(
    const float* __restrict__ X, const float* __restrict__ w,
    const float* __restrict__ b, bf16* __restrict__ Y)
{
    int row = blockIdx.x;
    const float4* xp = (const float4*)(X + (size_t)row * 1024);
    float4 xv = xp[threadIdx.x];
    float s  = xv.x + xv.y + xv.z + xv.w;
    float ss = xv.x*xv.x + xv.y*xv.y + xv.z*xv.z + xv.w*xv.w;
    #pragma unroll
    for (int off = 32; off > 0; off >>= 1) {
        s  += __shfl_down(s, off);
        ss += __shfl_down(ss, off);
    }
    __shared__ float rs[4], rss[4];
    int wave = threadIdx.x >> 6, lane = threadIdx.x & 63;
    if (lane == 0) { rs[wave] = s; rss[wave] = ss; }
    __syncthreads();
    s  = rs[0] + rs[1] + rs[2] + rs[3];
    ss = rss[0] + rss[1] + rss[2] + rss[3];
    float mu  = s * (1.f / 1024.f);
    float var = ss * (1.f / 1024.f) - mu * mu;
    float rstd = rsqrtf(var + 1e-5f);
    float4 wv = ((const float4*)w)[threadIdx.x];
    float4 bv = ((const float4*)b)[threadIdx.x];
    bf16x4 y;
    y[0] = (bf16)((xv.x - mu) * rstd * wv.x + bv.x);
    y[1] = (bf16)((xv.y - mu) * rstd * wv.y + bv.y);
    y[2] = (bf16)((xv.z - mu) * rstd * wv.z + bv.z);
    y[3] = (bf16)((xv.w - mu) * rstd * wv.w + bv.w);
    *(bf16x4*)(Y + (size_t)row * 1024 + threadIdx.x * 4) = y;
}

// ---------------- weight fp32[N,K] -> bf16[Np,Kp] with zero pad ------------
__global__ __launch_bounds__(256) void convertw_kernel(
    const float* __restrict__ src, bf16* __restrict__ dst,
    int N, int K, int Np, int Kp)
{
    int idx = blockIdx.x * 256 + threadIdx.x;
    int groups = Np * (Kp >> 3);
    if (idx >= groups) return;
    int r  = idx / (Kp >> 3);
    int kc = (idx - r * (Kp >> 3)) << 3;
    bf16x8 o;
    if (r < N && kc < K) {
        float4 f0 = *(const float4*)(src + (size_t)r * K + kc);
        float4 f1 = *(const float4*)(src + (size_t)r * K + kc + 4);
        o[0]=(bf16)f0.x; o[1]=(bf16)f0.y; o[2]=(bf16)f0.z; o[3]=(bf16)f0.w;
        o[4]=(bf16)f1.x; o[5]=(bf16)f1.y; o[6]=(bf16)f1.z; o[7]=(bf16)f1.w;
    } else {
        #pragma unroll
        for (int j = 0; j < 8; ++j) o[j] = (bf16)0.f;
    }
    *(bf16x8*)(dst + (size_t)r * Kp + kc) = o;
}

// ---------------- pad bias fp32[1512] -> fp32[1536] ------------------------
__global__ __launch_bounds__(256) void padbias_kernel(
    const float* __restrict__ src, float* __restrict__ dst)
{
    int i = blockIdx.x * 256 + threadIdx.x;
    if (i < 1536) dst[i] = (i < 1512) ? src[i] : 0.f;
}

// ---------------- bf16 MFMA GEMM: C = A[M,Kp] @ W[Np,Kp]^T + bias ----------
// EPI: 0 = bf16 out (qkv), 1 = exact gelu -> bf16 out, 2 = +R -> fp32 out
__device__ __forceinline__ float gelu_exact(float v)
{
    return 0.5f * v * (1.f + erff(v * 0.70710678118654752f));
}

template<int EPI>
__global__ __launch_bounds__(256) void gemm_bf16_kernel(
    const bf16* __restrict__ A, const bf16* __restrict__ Wt,
    const float* __restrict__ bias, const float* R,
    float* Cf, bf16* Cb, int N, int Kp)
{
    __shared__ bf16 As[128][32];
    __shared__ bf16 Bs[128][32];
    const int tid  = threadIdx.x;
    const int w    = tid >> 6;
    const int lane = tid & 63;
    const int row0 = blockIdx.y * 128;
    const int col0 = blockIdx.x * 128;
    const int wr = (w >> 1) * 64;       // wave row offset in tile
    const int wc = (w & 1) * 64;        // wave col offset in tile

    const char* Abase = (const char*)(A + (size_t)row0 * Kp);
    const char* Wbase = (const char*)(Wt + (size_t)col0 * Kp);
    const size_t strideB = (size_t)Kp * 2;

    f32x4 acc[4][4] = {};
    const int kiters = Kp >> 5;
    const int rl = lane & 15;
    const int kb = (lane >> 4) * 8;     // bf16 elem offset within 32-wide k

    for (int kt = 0; kt < kiters; ++kt) {
        __syncthreads();                // prev readers done before overwrite
        #pragma unroll
        for (int it = 0; it < 2; ++it) {
            int o = (it * 256 + tid) * 16;      // byte offset in 8KB tile
            int r = o >> 6;                     // 64B per LDS row (32 bf16)
            int kbyte = o & 63;
            __builtin_amdgcn_global_load_lds(
                (const __attribute__((address_space(1))) void*)
                    (Abase + (size_t)r * strideB + (size_t)kt * 64 + kbyte),
                (__attribute__((address_space(3))) void*)((char*)&As[0][0] + o),
                16, 0, 0);
            __builtin_amdgcn_global_load_lds(
                (const __attribute__((address_space(1))) void*)
                    (Wbase + (size_t)r * strideB + (size_t)kt * 64 + kbyte),
                (__attribute__((address_space(3))) void*)((char*)&Bs[0][0] + o),
                16, 0, 0);
        }
        __syncthreads();                // drains vmcnt before barrier
        bf16x8 af[4], bfr[4];
        #pragma unroll
        for (int i = 0; i < 4; ++i) {
            af[i]  = *(const bf16x8*)&As[wr + i*16 + rl][kb];
            bfr[i] = *(const bf16x8*)&Bs[wc + i*16 + rl][kb];
        }
        #pragma unroll
        for (int mi = 0; mi < 4; ++mi)
            #pragma unroll
            for (int nj = 0; nj < 4; ++nj)
                acc[mi][nj] = __builtin_amdgcn_mfma_f32_16x16x32_bf16(
                    af[mi], bfr[nj], acc[mi][nj], 0, 0, 0);
    }

    // C/D layout: col = lane&15, row = (lane>>4)*4 + reg   [m89/m91]
    const int rq = (lane >> 4) * 4;
    #pragma unroll
    for (int mi = 0; mi < 4; ++mi) {
        #pragma unroll
        for (int rj = 0; rj < 4; ++rj) {
            int row = row0 + wr + mi*16 + rq + rj;
            #pragma unroll
            for (int nj = 0; nj < 4; ++nj) {
                int col = col0 + wc + nj*16 + rl;
                float c = acc[mi][nj][rj] + bias[col];
                size_t off = (size_t)row * N + col;
                if (EPI == 0)      Cb[off] = (bf16)c;
                else if (EPI == 1) Cb[off] = (bf16)gelu_exact(c);
                else               Cf[off] = c + R[off];
            }
        }
    }
}

// ---------------- windowed attention, one wave per (b,h,t) token ----------
// qkv bf16 [2048][1536], out bf16 [2048][512] (cols 504..511 zeroed)
__global__ __launch_bounds__(256) void attn_kernel(
    const bf16* __restrict__ qkv, const float* __restrict__ rel_pos,
    bf16* __restrict__ outp)
{
    __shared__ float sbias[64*65];      // bias[d][v] at d*65+v
    __shared__ float kmw[4][3][64];
    for (int i = threadIdx.x; i < 63*63; i += 256) {
        int d = i / 63, v = i - d*63;
        sbias[d*65 + v] = rel_pos[((d + 32) % 63) * 63 + v];
    }
    __syncthreads();
    const int wave = threadIdx.x >> 6;
    const int lane = threadIdx.x & 63;
    const int tk  = blockIdx.x * 4 + wave;
    const int row = tk >> 3;
    const int h   = tk & 7;
    const bf16* base = qkv + (size_t)row * 1536 + h * 63;
    float q_own = 0.f, k_own = 0.f, v_own = 0.f;
    if (lane < 63) {
        q_own = (float)base[lane];
        k_own = (float)base[504 + lane];
        v_own = (float)base[1008 + lane];
    }
    // phase A: lane = column v; per-column max + exp-sum over d
    float m = -1e30f;
    for (int d = 0; d < 63; ++d) {
        float qd = __shfl(q_own, d);
        m = fmaxf(m, fmaf(qd, k_own, sbias[d*65 + lane]));
    }
    float Z = 0.f;
    for (int d = 0; d < 63; ++d) {
        float qd = __shfl(q_own, d);
        Z += __expf(fmaf(qd, k_own, sbias[d*65 + lane]) - m);
    }
    kmw[wave][0][lane] = k_own;
    kmw[wave][1][lane] = m;
    kmw[wave][2][lane] = v_own / Z;
    // same-wave LDS write->read, program order
    float acc = 0.f;
    for (int v = 0; v < 63; ++v) {
        float s = fmaf(q_own, kmw[wave][0][v], sbias[lane*65 + v]) - kmw[wave][1][v];
        acc += __expf(s) * kmw[wave][2][v];
    }
    if (lane < 63)
        outp[(size_t)row * 512 + h*63 + lane] = (bf16)acc;
    if (h == 7 && lane == 63) {         // zero the K-pad columns 504..511
        #pragma unroll
        for (int j = 0; j < 8; ++j)
            outp[(size_t)row * 512 + 504 + j] = (bf16)0.f;
    }
}

extern "C" void kernel_launch(void* const* d_in, const int* in_sizes, int n_in,
                              void* d_out, int out_size, void* d_ws, size_t ws_size,
                              hipStream_t stream)
{
    const float* x       = (const float*)d_in[0];
    const float* ln1_w   = (const float*)d_in[1];
    const float* ln1_b   = (const float*)d_in[2];
    const float* qkv_w   = (const float*)d_in[3];
    const float* qkv_b   = (const float*)d_in[4];
    const float* rel_pos = (const float*)d_in[5];
    const float* proj_w  = (const float*)d_in[6];
    const float* proj_b  = (const float*)d_in[7];
    const float* ln2_w   = (const float*)d_in[8];
    const float* ln2_b   = (const float*)d_in[9];
    const float* fc_w    = (const float*)d_in[10];
    const float* fc_b    = (const float*)d_in[11];
    const float* cproj_w = (const float*)d_in[12];
    const float* cproj_b = (const float*)d_in[13];
    float* out = (float*)d_out;

    // ---- workspace layout (bytes), total ~50.0 MB ----
    char* p = (char*)d_ws;
    float* xr      = (float*)p;            p += (size_t)2048*1024*4;   // 8 MB
    bf16*  h_bf    = (bf16*)p;             p += (size_t)2048*1024*2;   // 4 MB
    bf16*  wqkv    = (bf16*)p;             p += (size_t)1536*1024*2;   // 3 MB
    bf16*  wproj   = (bf16*)p;             p += (size_t)1024*512*2;    // 1 MB
    bf16*  wfc     = (bf16*)p;             p += (size_t)4096*1024*2;   // 8 MB
    bf16*  wcproj  = (bf16*)p;             p += (size_t)1024*4096*2;   // 8 MB
    float* qkvb_p  = (float*)p;            p += 8192;                  // 6 KB pad
    bf16*  attn_bf = (bf16*)p;             p += (size_t)2048*512*2;    // 2 MB
    bf16*  qkvb    = (bf16*)p;                                         // 6 MB...
    bf16*  fc_act  = (bf16*)p;             // fc_act overlaps qkvb (dead by then), 16 MB

    // weight/bias conversions (deterministic, every call)
    convertw_kernel<<<(1536*128+255)/256, 256, 0, stream>>>(qkv_w,  wqkv,  1512, 1024, 1536, 1024);
    convertw_kernel<<<(1024*64 +255)/256, 256, 0, stream>>>(proj_w, wproj, 1024,  504, 1024,  512);
    convertw_kernel<<<(4096*128+255)/256, 256, 0, stream>>>(fc_w,   wfc,   4096, 1024, 4096, 1024);
    convertw_kernel<<<(1024*512+255)/256, 256, 0, stream>>>(cproj_w,wcproj,1024, 4096, 1024, 4096);
    padbias_kernel<<<6, 256, 0, stream>>>(qkv_b, qkvb_p);

    rotary_kernel<<<2048, 256, 0, stream>>>(x, xr);
    ln_bf16_kernel<<<2048, 256, 0, stream>>>(xr, ln1_w, ln1_b, h_bf);
    gemm_bf16_kernel<0><<<dim3(12,16), 256, 0, stream>>>(h_bf, wqkv, qkvb_p, nullptr,
                                                         nullptr, qkvb, 1536, 1024);
    attn_kernel<<<4096, 256, 0, stream>>>(qkvb, rel_pos, attn_bf);
    gemm_bf16_kernel<2><<<dim3(8,16), 256, 0, stream>>>(attn_bf, wproj, proj_b, xr,
                                                        out, nullptr, 1024, 512);
    ln_bf16_kernel<<<2048, 256, 0, stream>>>(out, ln2_w, ln2_b, h_bf);
    gemm_bf16_kernel<1><<<dim3(32,16), 256, 0, stream>>>(h_bf, wfc, fc_b, nullptr,
                                                         nullptr, fc_act, 4096, 1024);
    gemm_bf16_kernel<2><<<dim3(8,16), 256, 0, stream>>>(fc_act, wcproj, cproj_b, out,
                                                        out, nullptr, 1024, 4096);
}

// Round 3
// 163.500 us; speedup vs baseline: 6.2412x; 1.5569x over previous
//
#include <hip/hip_runtime.h>
#include <hip/hip_bf16.h>

// Shapes (fixed): B=2 T=1024 E=1024 H=8 W=31 D=63
// NTOK=2048, H*D=504 (pad 512), 3*H*D=1512 (pad 1536), 4E=4096

typedef __bf16 bf16;
typedef bf16 bf16x8 __attribute__((ext_vector_type(8)));
typedef bf16 bf16x2 __attribute__((ext_vector_type(2)));
typedef float f32x4 __attribute__((ext_vector_type(4)));

// ---------------- fused rotary + layernorm1 --------------------------------
// xr = [sin(x*invf) | cos(x*invf)] (fp32, kept for residual), Y = LN(xr) bf16
__global__ __launch_bounds__(256) void rotary_ln_kernel(
    const float* __restrict__ x, const float* __restrict__ w,
    const float* __restrict__ b, float* __restrict__ xr, bf16* __restrict__ Y)
{
    const int row = blockIdx.x;
    const int tid = threadIdx.x;
    float2 xv = *(const float2*)(x + (size_t)row * 512 + tid * 2);
    float i0 = exp2f(-(float)(2*tid)     * 0.025952563241307518f);
    float i1 = exp2f(-(float)(2*tid + 1) * 0.025952563241307518f);
    float a0 = xv.x * i0, a1 = xv.y * i1;
    float s0 = sinf(a0), s1 = sinf(a1);
    float c0 = cosf(a0), c1 = cosf(a1);
    *(float2*)(xr + (size_t)row * 1024 + tid*2)       = make_float2(s0, s1);
    *(float2*)(xr + (size_t)row * 1024 + 512 + tid*2) = make_float2(c0, c1);
    float s  = s0 + s1 + c0 + c1;
    float ss = s0*s0 + s1*s1 + c0*c0 + c1*c1;
    #pragma unroll
    for (int off = 32; off > 0; off >>= 1) {
        s  += __shfl_down(s, off);
        ss += __shfl_down(ss, off);
    }
    __shared__ float rs[4], rss[4];
    int wave = tid >> 6, lane = tid & 63;
    if (lane == 0) { rs[wave] = s; rss[wave] = ss; }
    __syncthreads();
    s  = rs[0] + rs[1] + rs[2] + rs[3];
    ss = rss[0] + rss[1] + rss[2] + rss[3];
    float mu   = s * (1.f / 1024.f);
    float var  = ss * (1.f / 1024.f) - mu * mu;
    float rstd = rsqrtf(var + 1e-5f);
    float2 w0 = *(const float2*)(w + tid*2);
    float2 b0 = *(const float2*)(b + tid*2);
    float2 w1 = *(const float2*)(w + 512 + tid*2);
    float2 b1 = *(const float2*)(b + 512 + tid*2);
    bf16x2 y0, y1;
    y0[0] = (bf16)((s0 - mu) * rstd * w0.x + b0.x);
    y0[1] = (bf16)((s1 - mu) * rstd * w0.y + b0.y);
    y1[0] = (bf16)((c0 - mu) * rstd * w1.x + b1.x);
    y1[1] = (bf16)((c1 - mu) * rstd * w1.y + b1.y);
    *(bf16x2*)(Y + (size_t)row * 1024 + tid*2)       = y0;
    *(bf16x2*)(Y + (size_t)row * 1024 + 512 + tid*2) = y1;
}

// ---------------- layernorm (fp32 in, bf16 out), one block per row --------
__global__ __launch_bounds__(256) void ln_bf16_kernel(
    const float* __restrict__ X, const float* __restrict__ w,
    const float* __restrict__ b, bf16* __restrict__ Y)
{
    int row = blockIdx.x;
    const float4* xp = (const float4*)(X + (size_t)row * 1024);
    float4 xv = xp[threadIdx.x];
    float s  = xv.x + xv.y + xv.z + xv.w;
    float ss = xv.x*xv.x + xv.y*xv.y + xv.z*xv.z + xv.w*xv.w;
    #pragma unroll
    for (int off = 32; off > 0; off >>= 1) {
        s  += __shfl_down(s, off);
        ss += __shfl_down(ss, off);
    }
    __shared__ float rs[4], rss[4];
    int wave = threadIdx.x >> 6, lane = threadIdx.x & 63;
    if (lane == 0) { rs[wave] = s; rss[wave] = ss; }
    __syncthreads();
    s  = rs[0] + rs[1] + rs[2] + rs[3];
    ss = rss[0] + rss[1] + rss[2] + rss[3];
    float mu  = s * (1.f / 1024.f);
    float var = ss * (1.f / 1024.f) - mu * mu;
    float rstd = rsqrtf(var + 1e-5f);
    float4 wv = ((const float4*)w)[threadIdx.x];
    float4 bv = ((const float4*)b)[threadIdx.x];
    bf16 y[4];
    y[0] = (bf16)((xv.x - mu) * rstd * wv.x + bv.x);
    y[1] = (bf16)((xv.y - mu) * rstd * wv.y + bv.y);
    y[2] = (bf16)((xv.z - mu) * rstd * wv.z + bv.z);
    y[3] = (bf16)((xv.w - mu) * rstd * wv.w + bv.w);
    *(uint2*)(Y + (size_t)row * 1024 + threadIdx.x * 4) = *(uint2*)y;
}

// ---------------- fused weight converts (fp32->bf16, zero-pad) + bias pad --
__device__ __forceinline__ void conv_chunk(
    const float* __restrict__ src, bf16* __restrict__ dst,
    int ci, int N, int K, int Kp)
{
    int kpc = Kp >> 3;
    int r  = ci / kpc;
    int kc = (ci - r * kpc) << 3;
    bf16x8 o;
    if (r < N && kc < K) {
        float4 f0 = *(const float4*)(src + (size_t)r * K + kc);
        float4 f1 = *(const float4*)(src + (size_t)r * K + kc + 4);
        o[0]=(bf16)f0.x; o[1]=(bf16)f0.y; o[2]=(bf16)f0.z; o[3]=(bf16)f0.w;
        o[4]=(bf16)f1.x; o[5]=(bf16)f1.y; o[6]=(bf16)f1.z; o[7]=(bf16)f1.w;
    } else {
        #pragma unroll
        for (int j = 0; j < 8; ++j) o[j] = (bf16)0.f;
    }
    *(bf16x8*)(dst + (size_t)r * Kp + kc) = o;
}

__global__ __launch_bounds__(256) void conv_all_kernel(
    const float* __restrict__ qkv_w, const float* __restrict__ proj_w,
    const float* __restrict__ fc_w,  const float* __restrict__ cproj_w,
    const float* __restrict__ qkv_b,
    bf16* __restrict__ wqkv, bf16* __restrict__ wproj,
    bf16* __restrict__ wfc,  bf16* __restrict__ wcproj,
    float* __restrict__ qkvb_p)
{
    // chunk ranges (each chunk = 8 bf16): qkv 196608 | proj 65536 | fc 524288 | cproj 524288
    if (blockIdx.x == 5120) {
        for (int i = threadIdx.x; i < 1536; i += 256)
            qkvb_p[i] = (i < 1512) ? qkv_b[i] : 0.f;
        return;
    }
    int idx = blockIdx.x * 256 + threadIdx.x;
    if      (idx < 196608)  conv_chunk(qkv_w,   wqkv,   idx,          1512, 1024, 1024);
    else if (idx < 262144)  conv_chunk(proj_w,  wproj,  idx - 196608, 1024,  504,  512);
    else if (idx < 786432)  conv_chunk(fc_w,    wfc,    idx - 262144, 4096, 1024, 1024);
    else                    conv_chunk(cproj_w, wcproj, idx - 786432, 1024, 4096, 4096);
}

// ---------------- bf16 MFMA GEMM, 2-phase double-buffered ------------------
// C = A[M,Kp] @ W[Np,Kp]^T + bias.  BM=128, BK=64, 4 waves (2x2).
// LDS per buffer: A planes [2][128][32], B planes [2][BN][32] (64B row stride
// -> 8-way read pattern, m97-proven). gload_lds dest linear; global source
// pre-permuted per lane (m173).
// EPI: 0 = bf16 out, 1 = exact gelu -> bf16 out, 2 = +R -> fp32 out
__device__ __forceinline__ float gelu_exact(float v)
{
    return 0.5f * v * (1.f + erff(v * 0.70710678118654752f));
}

template<int BN, int EPI>
__global__ __launch_bounds__(256) void gemm2_kernel(
    const bf16* __restrict__ A, const bf16* __restrict__ Wt,
    const float* __restrict__ bias, const float* R,
    float* Cf, bf16* Cb, int N, int Kp)
{
    constexpr int N_REP = BN / 32;     // 16-col frags per wave
    constexpr int B_CH  = BN / 32;     // 16B staging chunks per thread for B
    constexpr int A_ELE = 128 * 64;    // bf16 elems per A buffer
    constexpr int B_ELE = BN * 64;
    __shared__ bf16 lds[2][A_ELE + B_ELE];

    const int tid  = threadIdx.x;
    const int w    = tid >> 6;
    const int lane = tid & 63;
    const int row0 = blockIdx.y * 128;
    const int col0 = blockIdx.x * BN;
    const int wr = (w >> 1) * 64;
    const int wc = (w & 1) * (BN / 2);
    const int rl = lane & 15;
    const int kb = (lane >> 4) * 8;

    const size_t strideB = (size_t)Kp * 2;   // bytes per row
    const char* Abase = (const char*)A  + (size_t)row0 * strideB;
    const char* Wbase = (const char*)Wt + (size_t)col0 * strideB;

    // plane-split source offsets (invariant over kt)
    size_t srcA[4], srcB[B_CH];
    #pragma unroll
    for (int i = 0; i < 4; ++i) {
        int q = (i * 256 + tid) * 16;
        int p = q >> 13;               // A plane = 8192 B
        int r = (q & 8191) >> 6;
        int c = q & 63;
        srcA[i] = (size_t)r * strideB + p * 64 + c;
    }
    #pragma unroll
    for (int i = 0; i < B_CH; ++i) {
        int q = (i * 256 + tid) * 16;
        int p = q / (B_ELE);           // B plane = BN*64 B
        int r = (q % (B_ELE)) >> 6;
        int c = q & 63;
        srcB[i] = (size_t)r * strideB + p * 64 + c;
    }

    f32x4 acc[4][N_REP] = {};

    auto STAGE = [&](int buf, int kt) {
        const char* ab = Abase + (size_t)kt * 128;
        const char* wb = Wbase + (size_t)kt * 128;
        char* ldsA = (char*)&lds[buf][0];
        char* ldsB = (char*)&lds[buf][A_ELE];
        #pragma unroll
        for (int i = 0; i < 4; ++i)
            __builtin_amdgcn_global_load_lds(
                (const __attribute__((address_space(1))) void*)(ab + srcA[i]),
                (__attribute__((address_space(3))) void*)(ldsA + (i*256 + tid)*16),
                16, 0, 0);
        #pragma unroll
        for (int i = 0; i < B_CH; ++i)
            __builtin_amdgcn_global_load_lds(
                (const __attribute__((address_space(1))) void*)(wb + srcB[i]),
                (__attribute__((address_space(3))) void*)(ldsB + (i*256 + tid)*16),
                16, 0, 0);
    };

    auto COMPUTE = [&](int buf) {
        #pragma unroll
        for (int ks = 0; ks < 2; ++ks) {
            bf16x8 af[4], bfr[N_REP];
            const bf16* pA = &lds[buf][ks * 4096];
            const bf16* pB = &lds[buf][A_ELE + ks * (B_ELE / 2)];
            #pragma unroll
            for (int mi = 0; mi < 4; ++mi)
                af[mi] = *(const bf16x8*)&pA[(wr + mi*16 + rl) * 32 + kb];
            #pragma unroll
            for (int nj = 0; nj < N_REP; ++nj)
                bfr[nj] = *(const bf16x8*)&pB[(wc + nj*16 + rl) * 32 + kb];
            #pragma unroll
            for (int mi = 0; mi < 4; ++mi)
                #pragma unroll
                for (int nj = 0; nj < N_REP; ++nj)
                    acc[mi][nj] = __builtin_amdgcn_mfma_f32_16x16x32_bf16(
                        af[mi], bfr[nj], acc[mi][nj], 0, 0, 0);
        }
    };

    const int niter = Kp >> 6;
    STAGE(0, 0);
    __syncthreads();                   // vmcnt(0)+barrier: buf0 ready
    int cur = 0;
    for (int kt = 0; kt < niter - 1; ++kt) {
        STAGE(cur ^ 1, kt + 1);        // issue next-tile loads first
        COMPUTE(cur);                  // hide latency under ds_read+MFMA
        __syncthreads();               // drain vmcnt + barrier once per tile
        cur ^= 1;
    }
    COMPUTE(cur);

    // C/D layout: col = lane&15, row = (lane>>4)*4 + reg   [m89/m91]
    const int rq = (lane >> 4) * 4;
    #pragma unroll
    for (int mi = 0; mi < 4; ++mi) {
        #pragma unroll
        for (int rj = 0; rj < 4; ++rj) {
            int row = row0 + wr + mi*16 + rq + rj;
            #pragma unroll
            for (int nj = 0; nj < N_REP; ++nj) {
                int col = col0 + wc + nj*16 + rl;
                float c = acc[mi][nj][rj] + bias[col];
                size_t off = (size_t)row * N + col;
                if (EPI == 0)      Cb[off] = (bf16)c;
                else if (EPI == 1) Cb[off] = (bf16)gelu_exact(c);
                else               Cf[off] = c + R[off];
            }
        }
    }
}

// ---------------- windowed attention, one wave per (b,h,t) token ----------
// qkv bf16 [2048][1536], out bf16 [2048][512] (cols 504..511 zeroed)
__global__ __launch_bounds__(256) void attn_kernel(
    const bf16* __restrict__ qkv, const float* __restrict__ rel_pos,
    bf16* __restrict__ outp)
{
    __shared__ float sbias[64*65];      // bias[d][v] at d*65+v
    __shared__ float kmw[4][3][64];
    for (int i = threadIdx.x; i < 63*63; i += 256) {
        int d = i / 63, v = i - d*63;
        sbias[d*65 + v] = rel_pos[((d + 32) % 63) * 63 + v];
    }
    __syncthreads();
    const int wave = threadIdx.x >> 6;
    const int lane = threadIdx.x & 63;
    const int tk  = blockIdx.x * 4 + wave;
    const int row = tk >> 3;
    const int h   = tk & 7;
    const bf16* base = qkv + (size_t)row * 1536 + h * 63;
    float q_own = 0.f, k_own = 0.f, v_own = 0.f;
    if (lane < 63) {
        q_own = (float)base[lane];
        k_own = (float)base[504 + lane];
        v_own = (float)base[1008 + lane];
    }
    // phase A: lane = column v; per-column max + exp-sum over d
    float m = -1e30f;
    for (int d = 0; d < 63; ++d) {
        float qd = __shfl(q_own, d);
        m = fmaxf(m, fmaf(qd, k_own, sbias[d*65 + lane]));
    }
    float Z = 0.f;
    for (int d = 0; d < 63; ++d) {
        float qd = __shfl(q_own, d);
        Z += __expf(fmaf(qd, k_own, sbias[d*65 + lane]) - m);
    }
    kmw[wave][0][lane] = k_own;
    kmw[wave][1][lane] = m;
    kmw[wave][2][lane] = v_own / Z;
    // same-wave LDS write->read, program order
    float acc = 0.f;
    for (int v = 0; v < 63; ++v) {
        float s = fmaf(q_own, kmw[wave][0][v], sbias[lane*65 + v]) - kmw[wave][1][v];
        acc += __expf(s) * kmw[wave][2][v];
    }
    if (lane < 63)
        outp[(size_t)row * 512 + h*63 + lane] = (bf16)acc;
    if (h == 7 && lane == 63) {         // zero the K-pad columns 504..511
        #pragma unroll
        for (int j = 0; j < 8; ++j)
            outp[(size_t)row * 512 + 504 + j] = (bf16)0.f;
    }
}

extern "C" void kernel_launch(void* const* d_in, const int* in_sizes, int n_in,
                              void* d_out, int out_size, void* d_ws, size_t ws_size,
                              hipStream_t stream)
{
    const float* x       = (const float*)d_in[0];
    const float* ln1_w   = (const float*)d_in[1];
    const float* ln1_b   = (const float*)d_in[2];
    const float* qkv_w   = (const float*)d_in[3];
    const float* qkv_b   = (const float*)d_in[4];
    const float* rel_pos = (const float*)d_in[5];
    const float* proj_w  = (const float*)d_in[6];
    const float* proj_b  = (const float*)d_in[7];
    const float* ln2_w   = (const float*)d_in[8];
    const float* ln2_b   = (const float*)d_in[9];
    const float* fc_w    = (const float*)d_in[10];
    const float* fc_b    = (const float*)d_in[11];
    const float* cproj_w = (const float*)d_in[12];
    const float* cproj_b = (const float*)d_in[13];
    float* out = (float*)d_out;

    // ---- workspace layout (bytes), total ~50 MB ----
    char* p = (char*)d_ws;
    float* xr      = (float*)p;            p += (size_t)2048*1024*4;   // 8 MB
    bf16*  h_bf    = (bf16*)p;             p += (size_t)2048*1024*2;   // 4 MB
    bf16*  wqkv    = (bf16*)p;             p += (size_t)1536*1024*2;   // 3 MB
    bf16*  wproj   = (bf16*)p;             p += (size_t)1024*512*2;    // 1 MB
    bf16*  wfc     = (bf16*)p;             p += (size_t)4096*1024*2;   // 8 MB
    bf16*  wcproj  = (bf16*)p;             p += (size_t)1024*4096*2;   // 8 MB
    float* qkvb_p  = (float*)p;            p += 8192;                  // 6 KB pad
    bf16*  attn_bf = (bf16*)p;             p += (size_t)2048*512*2;    // 2 MB
    bf16*  qkvb    = (bf16*)p;                                         // 6 MB
    bf16*  fc_act  = (bf16*)p;             // overlaps qkvb (dead after attn), 16 MB

    conv_all_kernel<<<5121, 256, 0, stream>>>(qkv_w, proj_w, fc_w, cproj_w, qkv_b,
                                              wqkv, wproj, wfc, wcproj, qkvb_p);
    rotary_ln_kernel<<<2048, 256, 0, stream>>>(x, ln1_w, ln1_b, xr, h_bf);
    gemm2_kernel<64,0><<<dim3(24,16), 256, 0, stream>>>(h_bf, wqkv, qkvb_p, nullptr,
                                                        nullptr, qkvb, 1536, 1024);
    attn_kernel<<<4096, 256, 0, stream>>>(qkvb, rel_pos, attn_bf);
    gemm2_kernel<64,2><<<dim3(16,16), 256, 0, stream>>>(attn_bf, wproj, proj_b, xr,
                                                        out, nullptr, 1024, 512);
    ln_bf16_kernel<<<2048, 256, 0, stream>>>(out, ln2_w, ln2_b, h_bf);
    gemm2_kernel<128,1><<<dim3(32,16), 256, 0, stream>>>(h_bf, wfc, fc_b, nullptr,
                                                         nullptr, fc_act, 4096, 1024);
    gemm2_kernel<64,2><<<dim3(16,16), 256, 0, stream>>>(fc_act, wcproj, cproj_b, out,
                                                        out, nullptr, 1024, 4096);
}

// Round 4
// 158.539 us; speedup vs baseline: 6.4365x; 1.0313x over previous
//
#include <hip/hip_runtime.h>
#include <hip/hip_bf16.h>

// Shapes (fixed): B=2 T=1024 E=1024 H=8 W=31 D=63
// NTOK=2048, H*D=504 (pad 512), 3*H*D=1512 (pad 1536), 4E=4096

typedef __bf16 bf16;
typedef bf16 bf16x8 __attribute__((ext_vector_type(8)));
typedef bf16 bf16x2 __attribute__((ext_vector_type(2)));
typedef float f32x4 __attribute__((ext_vector_type(4)));

// ---------------- fused rotary + layernorm1 --------------------------------
__global__ __launch_bounds__(256) void rotary_ln_kernel(
    const float* __restrict__ x, const float* __restrict__ w,
    const float* __restrict__ b, float* __restrict__ xr, bf16* __restrict__ Y)
{
    const int row = blockIdx.x;
    const int tid = threadIdx.x;
    float2 xv = *(const float2*)(x + (size_t)row * 512 + tid * 2);
    float i0 = exp2f(-(float)(2*tid)     * 0.025952563241307518f);
    float i1 = exp2f(-(float)(2*tid + 1) * 0.025952563241307518f);
    float a0 = xv.x * i0, a1 = xv.y * i1;
    float s0 = sinf(a0), s1 = sinf(a1);
    float c0 = cosf(a0), c1 = cosf(a1);
    *(float2*)(xr + (size_t)row * 1024 + tid*2)       = make_float2(s0, s1);
    *(float2*)(xr + (size_t)row * 1024 + 512 + tid*2) = make_float2(c0, c1);
    float s  = s0 + s1 + c0 + c1;
    float ss = s0*s0 + s1*s1 + c0*c0 + c1*c1;
    #pragma unroll
    for (int off = 32; off > 0; off >>= 1) {
        s  += __shfl_down(s, off);
        ss += __shfl_down(ss, off);
    }
    __shared__ float rs[4], rss[4];
    int wave = tid >> 6, lane = tid & 63;
    if (lane == 0) { rs[wave] = s; rss[wave] = ss; }
    __syncthreads();
    s  = rs[0] + rs[1] + rs[2] + rs[3];
    ss = rss[0] + rss[1] + rss[2] + rss[3];
    float mu   = s * (1.f / 1024.f);
    float var  = ss * (1.f / 1024.f) - mu * mu;
    float rstd = rsqrtf(var + 1e-5f);
    float2 w0 = *(const float2*)(w + tid*2);
    float2 b0 = *(const float2*)(b + tid*2);
    float2 w1 = *(const float2*)(w + 512 + tid*2);
    float2 b1 = *(const float2*)(b + 512 + tid*2);
    bf16x2 y0, y1;
    y0[0] = (bf16)((s0 - mu) * rstd * w0.x + b0.x);
    y0[1] = (bf16)((s1 - mu) * rstd * w0.y + b0.y);
    y1[0] = (bf16)((c0 - mu) * rstd * w1.x + b1.x);
    y1[1] = (bf16)((c1 - mu) * rstd * w1.y + b1.y);
    *(bf16x2*)(Y + (size_t)row * 1024 + tid*2)       = y0;
    *(bf16x2*)(Y + (size_t)row * 1024 + 512 + tid*2) = y1;
}

// ---------------- layernorm (fp32 in, bf16 out), one block per row --------
__global__ __launch_bounds__(256) void ln_bf16_kernel(
    const float* __restrict__ X, const float* __restrict__ w,
    const float* __restrict__ b, bf16* __restrict__ Y)
{
    int row = blockIdx.x;
    const float4* xp = (const float4*)(X + (size_t)row * 1024);
    float4 xv = xp[threadIdx.x];
    float s  = xv.x + xv.y + xv.z + xv.w;
    float ss = xv.x*xv.x + xv.y*xv.y + xv.z*xv.z + xv.w*xv.w;
    #pragma unroll
    for (int off = 32; off > 0; off >>= 1) {
        s  += __shfl_down(s, off);
        ss += __shfl_down(ss, off);
    }
    __shared__ float rs[4], rss[4];
    int wave = threadIdx.x >> 6, lane = threadIdx.x & 63;
    if (lane == 0) { rs[wave] = s; rss[wave] = ss; }
    __syncthreads();
    s  = rs[0] + rs[1] + rs[2] + rs[3];
    ss = rss[0] + rss[1] + rss[2] + rss[3];
    float mu  = s * (1.f / 1024.f);
    float var = ss * (1.f / 1024.f) - mu * mu;
    float rstd = rsqrtf(var + 1e-5f);
    float4 wv = ((const float4*)w)[threadIdx.x];
    float4 bv = ((const float4*)b)[threadIdx.x];
    bf16 y[4];
    y[0] = (bf16)((xv.x - mu) * rstd * wv.x + bv.x);
    y[1] = (bf16)((xv.y - mu) * rstd * wv.y + bv.y);
    y[2] = (bf16)((xv.z - mu) * rstd * wv.z + bv.z);
    y[3] = (bf16)((xv.w - mu) * rstd * wv.w + bv.w);
    *(uint2*)(Y + (size_t)row * 1024 + threadIdx.x * 4) = *(uint2*)y;
}

// ---------------- fused weight converts (fp32->bf16, zero-pad) + bias pad --
__device__ __forceinline__ void conv_chunk(
    const float* __restrict__ src, bf16* __restrict__ dst,
    int ci, int N, int K, int Kp)
{
    int kpc = Kp >> 3;
    int r  = ci / kpc;
    int kc = (ci - r * kpc) << 3;
    bf16x8 o;
    if (r < N && kc < K) {
        float4 f0 = *(const float4*)(src + (size_t)r * K + kc);
        float4 f1 = *(const float4*)(src + (size_t)r * K + kc + 4);
        o[0]=(bf16)f0.x; o[1]=(bf16)f0.y; o[2]=(bf16)f0.z; o[3]=(bf16)f0.w;
        o[4]=(bf16)f1.x; o[5]=(bf16)f1.y; o[6]=(bf16)f1.z; o[7]=(bf16)f1.w;
    } else {
        #pragma unroll
        for (int j = 0; j < 8; ++j) o[j] = (bf16)0.f;
    }
    *(bf16x8*)(dst + (size_t)r * Kp + kc) = o;
}

__global__ __launch_bounds__(256) void conv_all_kernel(
    const float* __restrict__ qkv_w, const float* __restrict__ proj_w,
    const float* __restrict__ fc_w,  const float* __restrict__ cproj_w,
    const float* __restrict__ qkv_b,
    bf16* __restrict__ wqkv, bf16* __restrict__ wproj,
    bf16* __restrict__ wfc,  bf16* __restrict__ wcproj,
    float* __restrict__ qkvb_p)
{
    if (blockIdx.x == 5120) {
        for (int i = threadIdx.x; i < 1536; i += 256)
            qkvb_p[i] = (i < 1512) ? qkv_b[i] : 0.f;
        return;
    }
    int idx = blockIdx.x * 256 + threadIdx.x;
    if      (idx < 196608)  conv_chunk(qkv_w,   wqkv,   idx,          1512, 1024, 1024);
    else if (idx < 262144)  conv_chunk(proj_w,  wproj,  idx - 196608, 1024,  504,  512);
    else if (idx < 786432)  conv_chunk(fc_w,    wfc,    idx - 262144, 4096, 1024, 1024);
    else                    conv_chunk(cproj_w, wcproj, idx - 786432, 1024, 4096, 4096);
}

// ---------------- counted vmcnt helper ------------------------------------
template<int N> __device__ __forceinline__ void vmwait()
{
    static_assert(N==0 || N==3 || N==4 || N==6 || N==8, "add literal");
    if constexpr      (N==0) asm volatile("s_waitcnt vmcnt(0)" ::: "memory");
    else if constexpr (N==3) asm volatile("s_waitcnt vmcnt(3)" ::: "memory");
    else if constexpr (N==4) asm volatile("s_waitcnt vmcnt(4)" ::: "memory");
    else if constexpr (N==6) asm volatile("s_waitcnt vmcnt(6)" ::: "memory");
    else if constexpr (N==8) asm volatile("s_waitcnt vmcnt(8)" ::: "memory");
}

// ---------------- bf16 MFMA GEMM, 4-buffer 2-deep counted-vmcnt pipeline ---
// C = A[M,Kp] @ W[Np,Kp]^T + bias.  BM=128, BK=32, 4 waves (2x2).
// Steady state: 3 stages (3L loads) in flight, wait to 2L before barrier ->
// prefetch spans the barrier (T3+T4). Buffer reuse distance 4, waves drift
// <=1 barrier interval -> no WAR race.
// EPI: 0 = bf16 out, 1 = exact gelu -> bf16 out, 2 = +R -> fp32 out
__device__ __forceinline__ float gelu_exact(float v)
{
    return 0.5f * v * (1.f + erff(v * 0.70710678118654752f));
}

template<int BN, int EPI>
__global__ __launch_bounds__(256, (BN==64) ? 3 : 2) void gemm4_kernel(
    const bf16* __restrict__ A, const bf16* __restrict__ Wt,
    const float* __restrict__ bias, const float* R,
    float* Cf, bf16* Cb, int N, int Kp)
{
    constexpr int N_REP = BN / 32;      // 16-col frags per wave
    constexpr int B_CH  = BN / 64;      // 16B staging chunks per thread for B
    constexpr int L     = 2 + B_CH;     // loads per stage per thread
    constexpr int A_ELE = 128 * 32;     // bf16 elems per A buffer (8 KB)
    constexpr int B_ELE = BN * 32;
    __shared__ bf16 lds[4][A_ELE + B_ELE];

    const int tid  = threadIdx.x;
    const int w    = tid >> 6;
    const int lane = tid & 63;
    const int row0 = blockIdx.y * 128;
    const int col0 = blockIdx.x * BN;
    const int wr = (w >> 1) * 64;
    const int wc = (w & 1) * (BN / 2);
    const int rl = lane & 15;
    const int kb = (lane >> 4) * 8;

    const size_t strideB = (size_t)Kp * 2;   // bytes per row
    const char* Abase = (const char*)A  + (size_t)row0 * strideB;
    const char* Wbase = (const char*)Wt + (size_t)col0 * strideB;

    // kt-invariant source offsets (linear LDS fill; LDS row = 64 B)
    size_t srcA[2], srcB[B_CH];
    #pragma unroll
    for (int i = 0; i < 2; ++i) {
        int o = (i * 256 + tid) * 16;
        srcA[i] = (size_t)(o >> 6) * strideB + (o & 63);
    }
    #pragma unroll
    for (int i = 0; i < B_CH; ++i) {
        int o = (i * 256 + tid) * 16;
        srcB[i] = (size_t)(o >> 6) * strideB + (o & 63);
    }

    f32x4 acc[4][N_REP] = {};

    auto STAGE = [&](int buf, int kt) {
        const char* ab = Abase + (size_t)kt * 64;
        const char* wb = Wbase + (size_t)kt * 64;
        char* ldsA = (char*)&lds[buf][0];
        char* ldsB = (char*)&lds[buf][A_ELE];
        #pragma unroll
        for (int i = 0; i < 2; ++i)
            __builtin_amdgcn_global_load_lds(
                (const __attribute__((address_space(1))) void*)(ab + srcA[i]),
                (__attribute__((address_space(3))) void*)(ldsA + (i*256 + tid)*16),
                16, 0, 0);
        #pragma unroll
        for (int i = 0; i < B_CH; ++i)
            __builtin_amdgcn_global_load_lds(
                (const __attribute__((address_space(1))) void*)(wb + srcB[i]),
                (__attribute__((address_space(3))) void*)(ldsB + (i*256 + tid)*16),
                16, 0, 0);
    };

    auto COMPUTE = [&](int buf) {
        bf16x8 af[4], bfr[N_REP];
        const bf16* pA = &lds[buf][0];
        const bf16* pB = &lds[buf][A_ELE];
        #pragma unroll
        for (int mi = 0; mi < 4; ++mi)
            af[mi] = *(const bf16x8*)&pA[(wr + mi*16 + rl) * 32 + kb];
        #pragma unroll
        for (int nj = 0; nj < N_REP; ++nj)
            bfr[nj] = *(const bf16x8*)&pB[(wc + nj*16 + rl) * 32 + kb];
        __builtin_amdgcn_s_setprio(1);
        #pragma unroll
        for (int mi = 0; mi < 4; ++mi)
            #pragma unroll
            for (int nj = 0; nj < N_REP; ++nj)
                acc[mi][nj] = __builtin_amdgcn_mfma_f32_16x16x32_bf16(
                    af[mi], bfr[nj], acc[mi][nj], 0, 0, 0);
        __builtin_amdgcn_s_setprio(0);
    };

    const int niter = Kp >> 5;          // BK = 32
    STAGE(0, 0);
    STAGE(1, 1);
    for (int kt = 0; kt < niter; ++kt) {
        if (kt + 2 < niter) {
            STAGE((kt + 2) & 3, kt + 2);
            vmwait<2 * L>();            // stage kt landed; kt+1/kt+2 in flight
        } else if (kt + 1 < niter) {
            vmwait<L>();                // stage kt landed; kt+1 in flight
        } else {
            vmwait<0>();                // last stage landed
        }
        __builtin_amdgcn_s_barrier();
        COMPUTE(kt & 3);
    }

    // C/D layout: col = lane&15, row = (lane>>4)*4 + reg   [m89/m91]
    const int rq = (lane >> 4) * 4;
    #pragma unroll
    for (int mi = 0; mi < 4; ++mi) {
        #pragma unroll
        for (int rj = 0; rj < 4; ++rj) {
            int row = row0 + wr + mi*16 + rq + rj;
            #pragma unroll
            for (int nj = 0; nj < N_REP; ++nj) {
                int col = col0 + wc + nj*16 + rl;
                float c = acc[mi][nj][rj] + bias[col];
                size_t off = (size_t)row * N + col;
                if (EPI == 0)      Cb[off] = (bf16)c;
                else if (EPI == 1) Cb[off] = (bf16)gelu_exact(c);
                else               Cf[off] = c + R[off];
            }
        }
    }
}

// ---------------- windowed attention, one wave per (b,h,t) token ----------
__global__ __launch_bounds__(256) void attn_kernel(
    const bf16* __restrict__ qkv, const float* __restrict__ rel_pos,
    bf16* __restrict__ outp)
{
    __shared__ float sbias[64*65];      // bias[d][v] at d*65+v
    __shared__ float kmw[4][3][64];
    for (int i = threadIdx.x; i < 63*63; i += 256) {
        int d = i / 63, v = i - d*63;
        sbias[d*65 + v] = rel_pos[((d + 32) % 63) * 63 + v];
    }
    __syncthreads();
    const int wave = threadIdx.x >> 6;
    const int lane = threadIdx.x & 63;
    const int tk  = blockIdx.x * 4 + wave;
    const int row = tk >> 3;
    const int h   = tk & 7;
    const bf16* base = qkv + (size_t)row * 1536 + h * 63;
    float q_own = 0.f, k_own = 0.f, v_own = 0.f;
    if (lane < 63) {
        q_own = (float)base[lane];
        k_own = (float)base[504 + lane];
        v_own = (float)base[1008 + lane];
    }
    float m = -1e30f;
    for (int d = 0; d < 63; ++d) {
        float qd = __shfl(q_own, d);
        m = fmaxf(m, fmaf(qd, k_own, sbias[d*65 + lane]));
    }
    float Z = 0.f;
    for (int d = 0; d < 63; ++d) {
        float qd = __shfl(q_own, d);
        Z += __expf(fmaf(qd, k_own, sbias[d*65 + lane]) - m);
    }
    kmw[wave][0][lane] = k_own;
    kmw[wave][1][lane] = m;
    kmw[wave][2][lane] = v_own / Z;
    float acc = 0.f;
    for (int v = 0; v < 63; ++v) {
        float s = fmaf(q_own, kmw[wave][0][v], sbias[lane*65 + v]) - kmw[wave][1][v];
        acc += __expf(s) * kmw[wave][2][v];
    }
    if (lane < 63)
        outp[(size_t)row * 512 + h*63 + lane] = (bf16)acc;
    if (h == 7 && lane == 63) {
        #pragma unroll
        for (int j = 0; j < 8; ++j)
            outp[(size_t)row * 512 + 504 + j] = (bf16)0.f;
    }
}

extern "C" void kernel_launch(void* const* d_in, const int* in_sizes, int n_in,
                              void* d_out, int out_size, void* d_ws, size_t ws_size,
                              hipStream_t stream)
{
    const float* x       = (const float*)d_in[0];
    const float* ln1_w   = (const float*)d_in[1];
    const float* ln1_b   = (const float*)d_in[2];
    const float* qkv_w   = (const float*)d_in[3];
    const float* qkv_b   = (const float*)d_in[4];
    const float* rel_pos = (const float*)d_in[5];
    const float* proj_w  = (const float*)d_in[6];
    const float* proj_b  = (const float*)d_in[7];
    const float* ln2_w   = (const float*)d_in[8];
    const float* ln2_b   = (const float*)d_in[9];
    const float* fc_w    = (const float*)d_in[10];
    const float* fc_b    = (const float*)d_in[11];
    const float* cproj_w = (const float*)d_in[12];
    const float* cproj_b = (const float*)d_in[13];
    float* out = (float*)d_out;

    // ---- workspace layout (bytes), total ~50 MB ----
    char* p = (char*)d_ws;
    float* xr      = (float*)p;            p += (size_t)2048*1024*4;   // 8 MB
    bf16*  h_bf    = (bf16*)p;             p += (size_t)2048*1024*2;   // 4 MB
    bf16*  wqkv    = (bf16*)p;             p += (size_t)1536*1024*2;   // 3 MB
    bf16*  wproj   = (bf16*)p;             p += (size_t)1024*512*2;    // 1 MB
    bf16*  wfc     = (bf16*)p;             p += (size_t)4096*1024*2;   // 8 MB
    bf16*  wcproj  = (bf16*)p;             p += (size_t)1024*4096*2;   // 8 MB
    float* qkvb_p  = (float*)p;            p += 8192;                  // 6 KB pad
    bf16*  attn_bf = (bf16*)p;             p += (size_t)2048*512*2;    // 2 MB
    bf16*  qkvb    = (bf16*)p;                                         // 6 MB
    bf16*  fc_act  = (bf16*)p;             // overlaps qkvb (dead after attn), 16 MB

    conv_all_kernel<<<5121, 256, 0, stream>>>(qkv_w, proj_w, fc_w, cproj_w, qkv_b,
                                              wqkv, wproj, wfc, wcproj, qkvb_p);
    rotary_ln_kernel<<<2048, 256, 0, stream>>>(x, ln1_w, ln1_b, xr, h_bf);
    gemm4_kernel<64,0><<<dim3(24,16), 256, 0, stream>>>(h_bf, wqkv, qkvb_p, nullptr,
                                                        nullptr, qkvb, 1536, 1024);
    attn_kernel<<<4096, 256, 0, stream>>>(qkvb, rel_pos, attn_bf);
    gemm4_kernel<64,2><<<dim3(16,16), 256, 0, stream>>>(attn_bf, wproj, proj_b, xr,
                                                        out, nullptr, 1024, 512);
    ln_bf16_kernel<<<2048, 256, 0, stream>>>(out, ln2_w, ln2_b, h_bf);
    gemm4_kernel<128,1><<<dim3(32,16), 256, 0, stream>>>(h_bf, wfc, fc_b, nullptr,
                                                         nullptr, fc_act, 4096, 1024);
    gemm4_kernel<64,2><<<dim3(16,16), 256, 0, stream>>>(fc_act, wcproj, cproj_b, out,
                                                        out, nullptr, 1024, 4096);
}